// Round 5
// baseline (208.367 us; speedup 1.0000x reference)
//
#include <hip/hip_runtime.h>
#include <stdint.h>

#define Nn 16384
#define Dd 128
#define Qq 4096
#define Ee 256

typedef __bf16 bf16x8 __attribute__((ext_vector_type(8)));
typedef float floatx16 __attribute__((ext_vector_type(16)));

__device__ __forceinline__ float fexp2(float x) {
#if __has_builtin(__builtin_amdgcn_exp2f)
  return __builtin_amdgcn_exp2f(x);
#else
  return exp2f(x);
#endif
}
// pack two f32 -> bf16x2 (round-half-up, 3 VALU ops)
__device__ __forceinline__ unsigned pk_bf(float lo, float hi) {
  return __builtin_amdgcn_perm(__float_as_uint(hi) + 0x8000u,
                               __float_as_uint(lo) + 0x8000u, 0x07060302u);
}
// async global->LDS, 16B per lane; lds dest = wave-uniform base + lane*16
__device__ __forceinline__ void stage16(const void* g, void* lds_uniform) {
  __builtin_amdgcn_global_load_lds(
      (const __attribute__((address_space(1))) unsigned int*)g,
      (__attribute__((address_space(3))) unsigned int*)lds_uniform, 16, 0, 0);
}

// ---- K1: LayerNorm -> tiled bf16 images for k_attn staging ---------------
// grid 512 = [b 2][tile 256 of 64 n-rows]; block 256.
// xn_t  per tile 16 KB: offset(kv,du) = (kv>>5)*8192+(du>>1)*1024+(du&1)*512+(kv&31)*16
//   (du = 16B unit of 8 d values) -> k_attn ax read (kb,s) is base+lane*16.
// xnT_t per tile 16 KB: offset(d,kvu) = (d>>5)*4096+(kvu>>1)*1024+(kvu&1)*512+(d&31)*16
//   (kvu = 16B unit of 8 kv values) -> k_attn bx read (dn,s2) is base+lane*16.
__global__ __launch_bounds__(256) void k_lnt(
    const float* __restrict__ x, const float* __restrict__ gamma,
    const float* __restrict__ beta, char* __restrict__ xn_t,
    char* __restrict__ xnT_t) {
  __shared__ __align__(16) uint2 lds2[64 * 32];  // [kv][8B d-quad], pos m^(kv&31)
  const int tid = threadIdx.x;
  const int bid = blockIdx.x;
  const int b = bid >> 8, t = bid & 255;
  const int r = tid >> 2, qd = tid & 3;

  const float4* xp = (const float4*)(x + ((size_t)(b * Nn + t * 64 + r)) * Dd + qd * 32);
  float4 v[8];
  float s = 0.f, s2 = 0.f;
#pragma unroll
  for (int i = 0; i < 8; ++i) {
    v[i] = xp[i];
    s += (v[i].x + v[i].y) + (v[i].z + v[i].w);
    s2 += (v[i].x * v[i].x + v[i].y * v[i].y) + (v[i].z * v[i].z + v[i].w * v[i].w);
  }
  s += __shfl_xor(s, 1); s2 += __shfl_xor(s2, 1);
  s += __shfl_xor(s, 2); s2 += __shfl_xor(s2, 2);
  float mu = s * (1.0f / 128.0f);
  float var = s2 * (1.0f / 128.0f) - mu * mu;
  float rs = rsqrtf(var + 1e-5f);

  const float4* gp = (const float4*)(gamma + qd * 32);
  const float4* bp = (const float4*)(beta + qd * 32);
  const int rk = r & 31;
#pragma unroll
  for (int i = 0; i < 8; ++i) {
    float4 g = gp[i], bt = bp[i];
    unsigned lo = pk_bf((v[i].x - mu) * rs * g.x + bt.x, (v[i].y - mu) * rs * g.y + bt.y);
    unsigned hi = pk_bf((v[i].z - mu) * rs * g.z + bt.z, (v[i].w - mu) * rs * g.w + bt.w);
    lds2[r * 32 + ((qd * 8 + i) ^ rk)] = make_uint2(lo, hi);
  }
  __syncthreads();

  const size_t tb = ((size_t)(b * 256 + t)) * 16384;
  // xn_t stores: per-wave contiguous 1 KB
#pragma unroll
  for (int p = 0; p < 4; ++p) {
    int u = p * 256 + tid;
    int kv = ((u >> 9) & 1) * 32 + (u & 31);
    int du = ((u >> 6) & 7) * 2 + ((u >> 5) & 1);
    uint2 a = lds2[kv * 32 + ((2 * du) ^ (kv & 31))];
    uint2 c = lds2[kv * 32 + ((2 * du + 1) ^ (kv & 31))];
    *(uint4*)(xn_t + tb + (size_t)u * 16) = make_uint4(a.x, a.y, c.x, c.y);
  }
  // xnT_t stores: thread owns one d row (d=(tid>>6)*32+(tid&31)), klow=(tid>>5)&1
  const int d = ((tid >> 6) << 5) + (tid & 31);
  const int klow = (tid >> 5) & 1;
  const int m0 = d >> 2;
  const unsigned sel = (d & 1) ? 0x07060302u : 0x05040100u;
#pragma unroll
  for (int e = 0; e < 4; ++e) {
    int kvu = 2 * e + klow;
    unsigned wv[8];
#pragma unroll
    for (int j = 0; j < 8; ++j) {
      int kv = kvu * 8 + j;
      uint2 uu = lds2[kv * 32 + (m0 ^ (kv & 31))];
      wv[j] = (d & 2) ? uu.y : uu.x;
    }
    uint4 o;
    o.x = __builtin_amdgcn_perm(wv[1], wv[0], sel);
    o.y = __builtin_amdgcn_perm(wv[3], wv[2], sel);
    o.z = __builtin_amdgcn_perm(wv[5], wv[4], sel);
    o.w = __builtin_amdgcn_perm(wv[7], wv[6], sel);
    *(uint4*)(xnT_t + tb + ((size_t)(tid >> 6)) * 4096 + e * 1024 + klow * 512 +
              (tid & 31) * 16) = o;
  }
}

// ---- K2: cross-attention, 64 q/wave, all-contiguous LDS ------------------
// grid 2*16*ns = [b][qtile 16 of 256 q][split ns]; block 256 = 4 waves x 64 q.
__global__ __launch_bounds__(256, 2) void k_attn(
    const char* __restrict__ xn_t, const char* __restrict__ xnT_t,
    const float* __restrict__ queries,
    float* __restrict__ o_part,              // [B][ns][Q][D]
    float* __restrict__ l_part,              // [B][ns][Q]
    int ns_log2, int niter) {
  __shared__ __align__(16) char lds[65536];
  char* lds_x = lds;            // 16 KB X tile
  char* lds_xt = lds + 16384;   // 16 KB Xt tile
  char* lds_p = lds + 32768;    // 32 KB: per-wave 8 KB P [2 g][32 q][8 kvu]

  const int bid = blockIdx.x;
  const int ns = 1 << ns_log2;
  const int split = bid & (ns - 1);
  const int qt = (bid >> ns_log2) & 15;
  const int b = bid >> (ns_log2 + 4);
  const int tid = threadIdx.x;
  const int wave = tid >> 6, lane = tid & 63;
  const int col = lane & 31, half = lane >> 5;
  const int qwbase = qt * 256 + wave * 64;

  // Q B-fragments cast in-kernel (prescaled by SCALE*log2e)
  const float QSC = 0.08838834764831845f * 1.4426950408889634f;
  uint4 qfr[16];
#pragma unroll
  for (int g = 0; g < 2; ++g)
#pragma unroll
    for (int s = 0; s < 8; ++s) {
      const float4* qp = (const float4*)(queries +
          (size_t)(qwbase + g * 32 + col) * Dd + s * 16 + half * 8);
      float4 q0 = qp[0], q1 = qp[1];
      qfr[g * 8 + s] = make_uint4(
          pk_bf(q0.x * QSC, q0.y * QSC), pk_bf(q0.z * QSC, q0.w * QSC),
          pk_bf(q1.x * QSC, q1.y * QSC), pk_bf(q1.z * QSC, q1.w * QSC));
    }

  const floatx16 fz = {0.f,0.f,0.f,0.f,0.f,0.f,0.f,0.f,0.f,0.f,0.f,0.f,0.f,0.f,0.f,0.f};
  floatx16 O[8];
#pragma unroll
  for (int k = 0; k < 8; ++k) O[k] = fz;
  float ls0 = 0.f, ls1 = 0.f;

  const char* gx = xn_t + ((size_t)(b * 256 + split * niter)) * 16384;
  const char* gxt = xnT_t + ((size_t)(b * 256 + split * niter)) * 16384;
  char* pw = lds_p + wave * 8192;

  for (int i = 0; i < niter; ++i) {
    const size_t ib = (size_t)i * 16384;
#pragma unroll
    for (int p = 0; p < 4; ++p) {
      int m = wave * 4 + p;
      stage16(gx + ib + m * 1024 + lane * 16, lds_x + m * 1024);
      stage16(gxt + ib + m * 1024 + lane * 16, lds_xt + m * 1024);
    }
    __syncthreads();

    // S^T[64 kv][64 q]: per kb (32 kv), both q-groups share ax
#pragma unroll
    for (int kb = 0; kb < 2; ++kb) {
      floatx16 S0 = fz, S1 = fz;
#pragma unroll
      for (int s = 0; s < 8; ++s) {
        bf16x8 ax = *(const bf16x8*)(lds_x + kb * 8192 + s * 1024 + half * 512 + col * 16);
        S0 = __builtin_amdgcn_mfma_f32_32x32x16_bf16(ax, *(const bf16x8*)&qfr[s], S0, 0, 0, 0);
        S1 = __builtin_amdgcn_mfma_f32_32x32x16_bf16(ax, *(const bf16x8*)&qfr[8 + s], S1, 0, 0, 0);
      }
      // exp + accumulate l + write P (per-wave region, in-wave DS order)
#pragma unroll
      for (int r4 = 0; r4 < 4; ++r4) {
        float a0 = fexp2(S0[4 * r4 + 0]), a1 = fexp2(S0[4 * r4 + 1]);
        float a2 = fexp2(S0[4 * r4 + 2]), a3 = fexp2(S0[4 * r4 + 3]);
        float b0 = fexp2(S1[4 * r4 + 0]), b1 = fexp2(S1[4 * r4 + 1]);
        float b2 = fexp2(S1[4 * r4 + 2]), b3 = fexp2(S1[4 * r4 + 3]);
        ls0 += (a0 + a1) + (a2 + a3);
        ls1 += (b0 + b1) + (b2 + b3);
        int kvu = 4 * kb + r4;
        int ofs = (kvu >> 1) * 1024 + (kvu & 1) * 512 + col * 16 + half * 8;
        *(uint2*)(pw + ofs) = make_uint2(pk_bf(a0, a1), pk_bf(a2, a3));
        *(uint2*)(pw + 4096 + ofs) = make_uint2(pk_bf(b0, b1), pk_bf(b2, b3));
      }
    }

    // O[64 q][128 d] += P . Xt ; bx shared across q-groups
#pragma unroll
    for (int s2 = 0; s2 < 4; ++s2) {
      bf16x8 ap0 = *(const bf16x8*)(pw + s2 * 1024 + half * 512 + col * 16);
      bf16x8 ap1 = *(const bf16x8*)(pw + 4096 + s2 * 1024 + half * 512 + col * 16);
#pragma unroll
      for (int dn = 0; dn < 4; ++dn) {
        bf16x8 bx = *(const bf16x8*)(lds_xt + dn * 4096 + s2 * 1024 + half * 512 + col * 16);
        O[dn] = __builtin_amdgcn_mfma_f32_32x32x16_bf16(ap0, bx, O[dn], 0, 0, 0);
        O[4 + dn] = __builtin_amdgcn_mfma_f32_32x32x16_bf16(ap1, bx, O[4 + dn], 0, 0, 0);
      }
    }
    __syncthreads();
  }

  // epilogue
  float lt0 = ls0 + __shfl_xor(ls0, 32);
  float lt1 = ls1 + __shfl_xor(ls1, 32);
  if (half == 0) {
    size_t lb = ((size_t)(b * ns + split)) * Qq + qwbase;
    l_part[lb + col] = lt0;
    l_part[lb + 32 + col] = lt1;
  }
  float* op = o_part + (((size_t)(b * ns + split)) * Qq + qwbase) * Dd;
#pragma unroll
  for (int g = 0; g < 2; ++g)
#pragma unroll
    for (int dn = 0; dn < 4; ++dn)
#pragma unroll
      for (int r = 0; r < 16; ++r) {
        int q = g * 32 + (r & 3) + 8 * (r >> 2) + 4 * half;
        op[(size_t)q * Dd + dn * 32 + col] = O[g * 4 + dn][r];
      }
}

// ---- K3: combine splits, normalize, trailing GEMM (32x32x16) -------------
// grid 256 = [b 2][qchunk 128 of 32 q]; block 256 = 4 waves (wave owns 64 E)
__global__ __launch_bounds__(256) void k_comb(
    const float* __restrict__ o_part, const float* __restrict__ l_part,
    const float* __restrict__ W, float* __restrict__ out, int ns) {
  __shared__ __align__(16) char lds_a[8192];   // [32 q][16 du], q^(du&7) swizzle
  __shared__ float lds_linv[32];
  const int bid = blockIdx.x;
  const int b = bid >> 7, qc = bid & 127;
  const int qbase = qc * 32;
  const int tid = threadIdx.x;
  const int wave = tid >> 6, lane = tid & 63;
  const int col = lane & 31, half = lane >> 5;

  // W cast in-kernel into B-fragments
  uint4 wfr[16];
#pragma unroll
  for (int et = 0; et < 2; ++et)
#pragma unroll
    for (int s = 0; s < 8; ++s) {
      const float4* wp = (const float4*)(W +
          (size_t)(wave * 64 + et * 32 + col) * Dd + s * 16 + half * 8);
      float4 w0 = wp[0], w1 = wp[1];
      wfr[et * 8 + s] = make_uint4(pk_bf(w0.x, w0.y), pk_bf(w0.z, w0.w),
                                   pk_bf(w1.x, w1.y), pk_bf(w1.z, w1.w));
    }

  if (tid < 32) {
    float l = 0.f;
    for (int s = 0; s < ns; ++s)
      l += l_part[(size_t)(b * ns + s) * Qq + qbase + tid];
    lds_linv[tid] = 1.0f / l;
  }
  __syncthreads();

#pragma unroll
  for (int i = 0; i < 4; ++i) {
    int idx = i * 256 + tid;      // 1024 float4 units: q = idx>>5, d4 = idx&31
    int q = idx >> 5, d4 = idx & 31;
    float4 acc = make_float4(0.f, 0.f, 0.f, 0.f);
    for (int s = 0; s < ns; ++s) {
      float4 v = *(const float4*)(o_part +
          ((size_t)(b * ns + s) * Qq + qbase + q) * Dd + d4 * 4);
      acc.x += v.x; acc.y += v.y; acc.z += v.z; acc.w += v.w;
    }
    float li = lds_linv[q];
    int du = d4 >> 1;
    int pos = (du >> 1) * 1024 + (du & 1) * 512 + ((q ^ (du & 7)) & 31) * 16 + (d4 & 1) * 8;
    *(uint2*)(lds_a + pos) =
        make_uint2(pk_bf(acc.x * li, acc.y * li), pk_bf(acc.z * li, acc.w * li));
  }
  __syncthreads();

  bf16x8 af[8];
#pragma unroll
  for (int s = 0; s < 8; ++s) {
    int du = 2 * s + half;
    af[s] = *(const bf16x8*)(lds_a + s * 1024 + half * 512 + ((col ^ (du & 7)) & 31) * 16);
  }

  const floatx16 fz = {0.f,0.f,0.f,0.f,0.f,0.f,0.f,0.f,0.f,0.f,0.f,0.f,0.f,0.f,0.f,0.f};
#pragma unroll
  for (int et = 0; et < 2; ++et) {
    floatx16 C = fz;
#pragma unroll
    for (int s = 0; s < 8; ++s) {
      bf16x8 bw = *(const bf16x8*)&wfr[et * 8 + s];
      C = __builtin_amdgcn_mfma_f32_32x32x16_bf16(af[s], bw, C, 0, 0, 0);
    }
#pragma unroll
    for (int r = 0; r < 16; ++r) {
      int q = qbase + (r & 3) + 8 * (r >> 2) + 4 * half;
      out[((size_t)b * Qq + q) * Ee + wave * 64 + et * 32 + col] = C[r];
    }
  }
}

// ---- launcher ------------------------------------------------------------
extern "C" void kernel_launch(void* const* d_in, const int* in_sizes, int n_in,
                              void* d_out, int out_size, void* d_ws, size_t ws_size,
                              hipStream_t stream) {
  const float* x = (const float*)d_in[0];
  const float* gamma = (const float*)d_in[1];
  const float* beta = (const float*)d_in[2];
  const float* queries = (const float*)d_in[3];
  const float* W = (const float*)d_in[4];
  float* out = (float*)d_out;

  char* w = (char*)d_ws;
  char* xn_t = w;                                  // 8 MB (2 x 256 tiles x 16 KB)
  char* xnT_t = w + (size_t)8 * 1024 * 1024;       // 8 MB
  float* o_part = (float*)(w + (size_t)16 * 1024 * 1024);

  // ns=16 needs 16M + 64M + 0.5M; fall back to ns=8 (fits proven 48.25M) otherwise
  const size_t need16 = (size_t)16 * 1024 * 1024 +
                        (size_t)2 * 16 * Qq * Dd * 4 + (size_t)2 * 16 * Qq * 4;
  int ns_log2 = (ws_size >= need16) ? 4 : 3;
  int ns = 1 << ns_log2;
  int niter = 256 / ns;   // 64-kv tiles per split
  float* l_part = (float*)(w + (size_t)16 * 1024 * 1024 +
                           (size_t)2 * ns * Qq * Dd * 4);

  k_lnt<<<dim3(512), dim3(256), 0, stream>>>(x, gamma, beta, xn_t, xnT_t);
  k_attn<<<dim3(2 * 16 * ns), dim3(256), 0, stream>>>(xn_t, xnT_t, queries,
                                                      o_part, l_part, ns_log2, niter);
  k_comb<<<dim3(256), dim3(256), 0, stream>>>(o_part, l_part, W, out, ns);
}